// Round 11
// baseline (134.926 us; speedup 1.0000x reference)
//
#include <hip/hip_runtime.h>
#include <stdint.h>

typedef _Float16 f16;
typedef _Float16 half8 __attribute__((ext_vector_type(8)));
typedef float f32x4 __attribute__((ext_vector_type(4)));

#define MFMA16(A, B, C) __builtin_amdgcn_mfma_f32_16x16x32_f16(A, B, C, 0, 0, 0)

#define GLOAD16(g, l) __builtin_amdgcn_global_load_lds( \
    (const __attribute__((address_space(1))) uint32_t*)(g), \
    (__attribute__((address_space(3))) uint32_t*)(l), 16, 0, 0)

__device__ inline uint32_t packh(f16 a, f16 b) {
    union { f16 h[2]; uint32_t u; } t;
    t.h[0] = a; t.h[1] = b;
    return t.u;
}

// ---------------------------------------------------------------------------
// Kernel 0: one-pass f32 -> f16 conversion of x, Wqkv, Wproj.
// ---------------------------------------------------------------------------
#define XE4 786432   // (8192*384)/4
#define WQ4 110592   // (1152*384)/4
#define WP4 36864    // (384*384)/4

__global__ __launch_bounds__(256) void convert_all(
    const float* __restrict__ x, const float* __restrict__ wq,
    const float* __restrict__ wp, f16* __restrict__ xo,
    f16* __restrict__ wqo, f16* __restrict__ wpo) {
    const int total = XE4 + WQ4 + WP4;
    for (int i = blockIdx.x * blockDim.x + threadIdx.x; i < total;
         i += gridDim.x * blockDim.x) {
        const float* src;
        f16* dst;
        int idx = i;
        if (idx < XE4) { src = x; dst = xo; }
        else if (idx < XE4 + WQ4) { idx -= XE4; src = wq; dst = wqo; }
        else { idx -= XE4 + WQ4; src = wp; dst = wpo; }
        float4 v = ((const float4*)src)[idx];
        union { f16 x[4]; uint2 u; } H;
        H.x[0] = (f16)v.x; H.x[1] = (f16)v.y;
        H.x[2] = (f16)v.z; H.x[3] = (f16)v.w;
        ((uint2*)dst)[idx] = H.u;
    }
}

// ---------------------------------------------------------------------------
// Kernel 1: qkv = x16 @ Wq16^T (unchanged from R10). 128x128 tile, BK=32,
// triple-buffered global_load_lds staging, 2-deep prefetch, vmcnt(8).
// grid (64, 9), block 256. LDS 48KB.
// ---------------------------------------------------------------------------
__global__ __launch_bounds__(256) void qkv_gemm(
    const f16* __restrict__ x16, const f16* __restrict__ w16,
    f16* __restrict__ q_, f16* __restrict__ k_, f16* __restrict__ vt_) {
    __shared__ f16 sA[3][4096], sB[3][4096];
    const int tid = threadIdx.x;
    const int w = tid >> 6, lane = tid & 63;
    const int g = lane >> 4, q = lane & 15;
    const int m0 = blockIdx.x * 128, j0 = blockIdx.y * 128;
    const int wm = (w >> 1) * 64, wn = (w & 1) * 64;
    const bool isV = (j0 >= 768);

    const char* gA = (const char*)x16 + (size_t)m0 * 768;
    const char* gB = (const char*)w16 + (size_t)j0 * 768;
    auto STAGE = [&](int buf, int ks) {
#pragma unroll
        for (int i = 0; i < 2; ++i) {
            const int r0 = 32 * w + i * 16;
            const int row = r0 + (lane >> 2);
            const int chs = ((lane & 3) ^ ((row & 6) >> 1)) << 4;
            GLOAD16(gA + (size_t)row * 768 + ks * 64 + chs, &sA[buf][r0 * 32]);
            GLOAD16(gB + (size_t)row * 768 + ks * 64 + chs, &sB[buf][r0 * 32]);
        }
    };

    f32x4 acc[4][4];
#pragma unroll
    for (int i = 0; i < 4; ++i)
#pragma unroll
        for (int j = 0; j < 4; ++j) acc[i][j] = (f32x4){0.f, 0.f, 0.f, 0.f};

    asm volatile("" ::: "memory");
    STAGE(0, 0);
    STAGE(1, 1);
    for (int ks = 0; ks < 12; ++ks) {
        const int cur = ks % 3;
        __builtin_amdgcn_s_barrier();
        if (ks < 10) {
            STAGE((ks + 2) % 3, ks + 2);
            asm volatile("s_waitcnt vmcnt(8)" ::: "memory");
        } else if (ks == 10) {
            asm volatile("s_waitcnt vmcnt(4)" ::: "memory");
        } else {
            asm volatile("s_waitcnt vmcnt(0)" ::: "memory");
        }
        __builtin_amdgcn_s_barrier();

        half8 am[4], bn[4];
#pragma unroll
        for (int mi = 0; mi < 4; ++mi) {
            const int row = wm + 16 * mi + q;
            const int ch = (g ^ ((row & 6) >> 1)) * 8;
            am[mi] = *(const half8*)&sA[cur][row * 32 + ch];
        }
#pragma unroll
        for (int nj = 0; nj < 4; ++nj) {
            const int row = wn + 16 * nj + q;
            const int ch = (g ^ ((row & 6) >> 1)) * 8;
            bn[nj] = *(const half8*)&sB[cur][row * 32 + ch];
        }
        __builtin_amdgcn_s_setprio(1);
        if (!isV) {
#pragma unroll
            for (int mi = 0; mi < 4; ++mi)
#pragma unroll
                for (int nj = 0; nj < 4; ++nj)
                    acc[mi][nj] = MFMA16(bn[nj], am[mi], acc[mi][nj]);
        } else {
#pragma unroll
            for (int mi = 0; mi < 4; ++mi)
#pragma unroll
                for (int nj = 0; nj < 4; ++nj)
                    acc[mi][nj] = MFMA16(am[mi], bn[nj], acc[mi][nj]);
        }
        __builtin_amdgcn_s_setprio(0);
    }

    if (!isV) {
        const int t = j0 / 384;
        const float sc = (t == 0) ? 0.125f : 1.0f;
        f16* dst = (t == 0) ? q_ : k_;
#pragma unroll
        for (int nj = 0; nj < 4; ++nj) {
            const int jb = j0 + wn + 16 * nj + 4 * g;
            const int h = (jb - t * 384) >> 6, d0 = jb & 63;
#pragma unroll
            for (int mi = 0; mi < 4; ++mi) {
                const int mg = m0 + wm + 16 * mi + q;
                const int b = mg >> 10, n = mg & 1023;
                const size_t base = (size_t)(b * 6 + h) * 65536 + (size_t)n * 64 + d0;
                union { f16 x[4]; uint2 u; } H;
#pragma unroll
                for (int r = 0; r < 4; ++r) H.x[r] = (f16)(acc[mi][nj][r] * sc);
                *(uint2*)&dst[base] = H.u;
            }
        }
    } else {
#pragma unroll
        for (int nj = 0; nj < 4; ++nj) {
            const int jc = j0 + wn + 16 * nj + q;
            const int h = (jc - 768) >> 6, d = jc & 63;
#pragma unroll
            for (int mi = 0; mi < 4; ++mi) {
                const int mg = m0 + wm + 16 * mi + 4 * g;
                const int b = mg >> 10, n = mg & 1023;
                const size_t bh = (size_t)(b * 6 + h);
                union { f16 x[4]; uint2 u; } HV;
#pragma unroll
                for (int r = 0; r < 4; ++r) HV.x[r] = (f16)acc[mi][nj][r];
                *(uint2*)&vt_[bh * 65536 + (size_t)d * 1024 + n] = HV.u;
            }
        }
    }
}

// ---------------------------------------------------------------------------
// Kernel 2: fused relu-attention, single-f16, 8-WAVE blocks (QBLK=128).
// KVBLK=64, double-buffered 32KB LDS, counted vmcnt(2), setprio.
// grid 384 1D: bh = id%48 (XCD-local), qtile = id/48 (128 rows).
// Per wave: 16 q-rows; staging 1 K + 1 V GLOAD per iter (8 rows each).
// ---------------------------------------------------------------------------
__global__ __launch_bounds__(512) void attn_mfma(
    const f16* __restrict__ q_, const f16* __restrict__ k_,
    const f16* __restrict__ vt_, const float* __restrict__ alpha,
    f16* __restrict__ ao_) {
    __shared__ f16 sK[2][4096], sV[2][4096];
    const int tid = threadIdx.x;
    const int w = tid >> 6, lane = tid & 63;
    const int g = lane >> 4, q = lane & 15;
    const int bh = blockIdx.x % 48, h = bh % 6;
    const int n0 = (blockIdx.x / 48) * 128;

    const size_t kbb = (size_t)bh * 131072;
    const int rl8 = lane >> 3, cl8 = lane & 7;

    // wave w stages rows [8w, 8w+8) of K and V^T (1 GLOAD each)
    auto STAGE = [&](int buf, int kt) {
        const size_t kb = kbb + (size_t)kt * 8192;   // K tile: 64 rows x 128B
        const size_t vb = kbb + (size_t)kt * 128;    // V^T col offset
        const int rloc = 8 * w + rl8;
        const int chs = (cl8 ^ (rloc & 7)) << 4;
        const int ldso = 8 * w * 64;
        GLOAD16((const char*)k_ + kb + (size_t)rloc * 128 + chs, &sK[buf][ldso]);
        GLOAD16((const char*)vt_ + vb + (size_t)rloc * 2048 + chs, &sV[buf][ldso]);
    };

    // Q fragments in registers (this wave's 16 rows)
    const size_t qbase = (size_t)bh * 65536 + (size_t)(n0 + 16 * w + q) * 64;
    half8 Qh[2];
    Qh[0] = *(const half8*)&q_[qbase + g * 8];
    Qh[1] = *(const half8*)&q_[qbase + 32 + g * 8];
    const float al = alpha[h];
    const float cg = (1.0f - al) * (1.0f / 1024.0f);
    const bool useLin = (cg != 0.0f);

    f32x4 accP[4], accS[4];
#pragma unroll
    for (int i = 0; i < 4; ++i) {
        accP[i] = (f32x4){0.f, 0.f, 0.f, 0.f};
        accS[i] = (f32x4){0.f, 0.f, 0.f, 0.f};
    }
    float rs = 0.f;

    asm volatile("" ::: "memory");
    STAGE(0, 0);
    int cur = 0;
    for (int kt = 0; kt < 16; ++kt) {
        __builtin_amdgcn_s_barrier();          // prev reads of buf^1 done
        if (kt < 15) {
            STAGE(cur ^ 1, kt + 1);
            asm volatile("s_waitcnt vmcnt(2)" ::: "memory");   // tile kt landed
        } else {
            asm volatile("s_waitcnt vmcnt(0)" ::: "memory");
        }
        __builtin_amdgcn_s_barrier();          // all waves' tile kt in LDS

        // ---- S^T = K·Q^T
        f32x4 sv[4];
        __builtin_amdgcn_s_setprio(1);
#pragma unroll
        for (int s = 0; s < 4; ++s) {
            f32x4 sa = (f32x4){0.f, 0.f, 0.f, 0.f};
            const int row = 16 * s + q;
#pragma unroll
            for (int k2 = 0; k2 < 2; ++k2) {
                const int ch = ((k2 * 4 + g) ^ (row & 7)) * 8;
                half8 kf = *(const half8*)&sK[cur][row * 64 + ch];
                sa = MFMA16(kf, Qh[k2], sa);
            }
            sv[s] = sa;
        }
        __builtin_amdgcn_s_setprio(0);

        // ---- relu + rowsum + pack to f16
        uint32_t pk[4][2];
#pragma unroll
        for (int s = 0; s < 4; ++s) {
            float p0 = fmaxf(sv[s][0], 0.f), p1 = fmaxf(sv[s][1], 0.f);
            float p2 = fmaxf(sv[s][2], 0.f), p3 = fmaxf(sv[s][3], 0.f);
            rs += (p0 + p1) + (p2 + p3);
            pk[s][0] = packh((f16)p0, (f16)p1);
            pk[s][1] = packh((f16)p2, (f16)p3);
        }

        // ---- butterfly P redistribution + out^T += V^T·P
#pragma unroll
        for (int t2 = 0; t2 < 2; ++t2) {
            union { uint32_t u[4]; half8 v; } fh;
#pragma unroll
            for (int r = 0; r < 4; ++r) {
                const int srcl = ((2 * g + (r >> 1)) & 3) * 16 + q;
                uint32_t a0 = __shfl(pk[2 * t2][r & 1], srcl, 64);
                uint32_t b0 = __shfl(pk[2 * t2 + 1][r & 1], srcl, 64);
                fh.u[r] = (g < 2) ? a0 : b0;
            }
            __builtin_amdgcn_s_setprio(1);
#pragma unroll
            for (int ds = 0; ds < 4; ++ds) {
                const int row = 16 * ds + q;
                const int ch = ((t2 * 4 + g) ^ (row & 7)) * 8;
                half8 vf = *(const half8*)&sV[cur][row * 64 + ch];
                accP[ds] = MFMA16(vf, fh.v, accP[ds]);
            }
            __builtin_amdgcn_s_setprio(0);
        }

        if (useLin) {     // linear branch (alpha != 1) — general correctness
            uint32_t sk[4][2];
#pragma unroll
            for (int s = 0; s < 4; ++s) {
                sk[s][0] = packh((f16)sv[s][0], (f16)sv[s][1]);
                sk[s][1] = packh((f16)sv[s][2], (f16)sv[s][3]);
            }
#pragma unroll
            for (int t2 = 0; t2 < 2; ++t2) {
                union { uint32_t u[4]; half8 v; } fh;
#pragma unroll
                for (int r = 0; r < 4; ++r) {
                    const int srcl = ((2 * g + (r >> 1)) & 3) * 16 + q;
                    uint32_t a0 = __shfl(sk[2 * t2][r & 1], srcl, 64);
                    uint32_t b0 = __shfl(sk[2 * t2 + 1][r & 1], srcl, 64);
                    fh.u[r] = (g < 2) ? a0 : b0;
                }
#pragma unroll
                for (int ds = 0; ds < 4; ++ds) {
                    const int row = 16 * ds + q;
                    const int ch = ((t2 * 4 + g) ^ (row & 7)) * 8;
                    half8 vf = *(const half8*)&sV[cur][row * 64 + ch];
                    accS[ds] = MFMA16(vf, fh.v, accS[ds]);
                }
            }
        }
        cur ^= 1;
    }

    rs += __shfl_xor(rs, 16, 64);
    rs += __shfl_xor(rs, 32, 64);
    const float inv = al / (rs + 1e-5f);

    const int b = bh / 6;
    const size_t arow = (size_t)(b * 1024 + n0 + 16 * w + q) * 384 + h * 64;
#pragma unroll
    for (int ds = 0; ds < 4; ++ds) {
        const int d0 = 16 * ds + 4 * g;
        union { f16 x[4]; uint2 u; } H;
#pragma unroll
        for (int r = 0; r < 4; ++r)
            H.x[r] = (f16)(accP[ds][r] * inv + cg * accS[ds][r]);
        *(uint2*)&ao_[arow + d0] = H.u;
    }
}

// ---------------------------------------------------------------------------
// Kernel 3: out = ao @ Wp16^T + bias (unchanged from R10). 64x128 tile,
// triple-buffered global_load_lds, 2-deep prefetch, vmcnt(6). grid (128, 3).
// ---------------------------------------------------------------------------
__global__ __launch_bounds__(256) void proj_gemm(
    const f16* __restrict__ a_, const f16* __restrict__ wp16,
    const float* __restrict__ bias, float* __restrict__ out) {
    __shared__ f16 sA[3][2048], sB[3][4096];
    const int tid = threadIdx.x;
    const int w = tid >> 6, lane = tid & 63;
    const int g = lane >> 4, q = lane & 15;
    const int m0 = blockIdx.x * 64, j0 = blockIdx.y * 128;
    const int wm = (w >> 1) * 32, wn = (w & 1) * 64;

    const char* gA = (const char*)a_ + (size_t)m0 * 768;
    const char* gB = (const char*)wp16 + (size_t)j0 * 768;
    auto STAGE = [&](int buf, int ks) {
        {
            const int r0 = 16 * w;
            const int row = r0 + (lane >> 2);
            const int chs = ((lane & 3) ^ ((row & 6) >> 1)) << 4;
            GLOAD16(gA + (size_t)row * 768 + ks * 64 + chs, &sA[buf][r0 * 32]);
        }
#pragma unroll
        for (int i = 0; i < 2; ++i) {
            const int r0 = 32 * w + i * 16;
            const int row = r0 + (lane >> 2);
            const int chs = ((lane & 3) ^ ((row & 6) >> 1)) << 4;
            GLOAD16(gB + (size_t)row * 768 + ks * 64 + chs, &sB[buf][r0 * 32]);
        }
    };

    f32x4 acc[2][4];
#pragma unroll
    for (int i = 0; i < 2; ++i)
#pragma unroll
        for (int j = 0; j < 4; ++j) acc[i][j] = (f32x4){0.f, 0.f, 0.f, 0.f};

    asm volatile("" ::: "memory");
    STAGE(0, 0);
    STAGE(1, 1);
    for (int ks = 0; ks < 12; ++ks) {
        const int cur = ks % 3;
        __builtin_amdgcn_s_barrier();
        if (ks < 10) {
            STAGE((ks + 2) % 3, ks + 2);
            asm volatile("s_waitcnt vmcnt(6)" ::: "memory");
        } else if (ks == 10) {
            asm volatile("s_waitcnt vmcnt(3)" ::: "memory");
        } else {
            asm volatile("s_waitcnt vmcnt(0)" ::: "memory");
        }
        __builtin_amdgcn_s_barrier();

        half8 am[2], bn[4];
#pragma unroll
        for (int mi = 0; mi < 2; ++mi) {
            const int row = wm + 16 * mi + q;
            const int ch = (g ^ ((row & 6) >> 1)) * 8;
            am[mi] = *(const half8*)&sA[cur][row * 32 + ch];
        }
#pragma unroll
        for (int nj = 0; nj < 4; ++nj) {
            const int row = wn + 16 * nj + q;
            const int ch = (g ^ ((row & 6) >> 1)) * 8;
            bn[nj] = *(const half8*)&sB[cur][row * 32 + ch];
        }
        __builtin_amdgcn_s_setprio(1);
#pragma unroll
        for (int mi = 0; mi < 2; ++mi)
#pragma unroll
            for (int nj = 0; nj < 4; ++nj)
                acc[mi][nj] = MFMA16(bn[nj], am[mi], acc[mi][nj]);
        __builtin_amdgcn_s_setprio(0);
    }

#pragma unroll
    for (int nj = 0; nj < 4; ++nj) {
        const int jb = j0 + wn + 16 * nj + 4 * g;
        const float4 bb = *(const float4*)&bias[jb];
#pragma unroll
        for (int mi = 0; mi < 2; ++mi) {
            const int m = m0 + wm + 16 * mi + q;
            float4 o;
            o.x = acc[mi][nj][0] + bb.x;
            o.y = acc[mi][nj][1] + bb.y;
            o.z = acc[mi][nj][2] + bb.z;
            o.w = acc[mi][nj][3] + bb.w;
            *(float4*)&out[(size_t)m * 384 + jb] = o;
        }
    }
}

// ---------------------------------------------------------------------------
extern "C" void kernel_launch(void* const* d_in, const int* in_sizes, int n_in,
                              void* d_out, int out_size, void* d_ws, size_t ws_size,
                              hipStream_t stream) {
    const float* x     = (const float*)d_in[0];
    const float* Wqkv  = (const float*)d_in[1];
    const float* Wproj = (const float*)d_in[2];
    const float* bproj = (const float*)d_in[3];
    const float* alpha = (const float*)d_in[4];
    float* out = (float*)d_out;

    f16* ws = (f16*)d_ws;
    const size_t XE = 8192 * 384;
    const size_t WQ = 1152 * 384;
    const size_t WP = 384 * 384;
    const size_t QE = 48 * 1024 * 64;

    f16* x16  = ws;            f16* wq16 = x16 + XE;
    f16* wp16 = wq16 + WQ;
    f16* qv   = wp16 + WP;     f16* kv   = qv + QE;
    f16* vt   = kv + QE;       f16* ao   = vt + QE;

    convert_all<<<1024, 256, 0, stream>>>(x, Wqkv, Wproj, x16, wq16, wp16);
    qkv_gemm<<<dim3(64, 9), 256, 0, stream>>>(x16, wq16, qv, kv, vt);
    attn_mfma<<<384, 512, 0, stream>>>(qv, kv, vt, alpha, ao);
    proj_gemm<<<dim3(128, 3), 256, 0, stream>>>(ao, wp16, bproj, out);
}

// Round 12
// 131.558 us; speedup vs baseline: 1.0256x; 1.0256x over previous
//
#include <hip/hip_runtime.h>
#include <stdint.h>

typedef _Float16 f16;
typedef _Float16 half8 __attribute__((ext_vector_type(8)));
typedef float f32x4 __attribute__((ext_vector_type(4)));

#define MFMA16(A, B, C) __builtin_amdgcn_mfma_f32_16x16x32_f16(A, B, C, 0, 0, 0)

#define GLOAD16(g, l) __builtin_amdgcn_global_load_lds( \
    (const __attribute__((address_space(1))) uint32_t*)(g), \
    (__attribute__((address_space(3))) uint32_t*)(l), 16, 0, 0)

__device__ inline uint32_t packh(f16 a, f16 b) {
    union { f16 h[2]; uint32_t u; } t;
    t.h[0] = a; t.h[1] = b;
    return t.u;
}

// ---------------------------------------------------------------------------
// Kernel 0: one-pass f32 -> f16 conversion of x, Wqkv, Wproj.
// ---------------------------------------------------------------------------
#define XE4 786432   // (8192*384)/4
#define WQ4 110592   // (1152*384)/4
#define WP4 36864    // (384*384)/4

__global__ __launch_bounds__(256) void convert_all(
    const float* __restrict__ x, const float* __restrict__ wq,
    const float* __restrict__ wp, f16* __restrict__ xo,
    f16* __restrict__ wqo, f16* __restrict__ wpo) {
    const int total = XE4 + WQ4 + WP4;
    for (int i = blockIdx.x * blockDim.x + threadIdx.x; i < total;
         i += gridDim.x * blockDim.x) {
        const float* src;
        f16* dst;
        int idx = i;
        if (idx < XE4) { src = x; dst = xo; }
        else if (idx < XE4 + WQ4) { idx -= XE4; src = wq; dst = wqo; }
        else { idx -= XE4 + WQ4; src = wp; dst = wpo; }
        float4 v = ((const float4*)src)[idx];
        union { f16 x[4]; uint2 u; } H;
        H.x[0] = (f16)v.x; H.x[1] = (f16)v.y;
        H.x[2] = (f16)v.z; H.x[3] = (f16)v.w;
        ((uint2*)dst)[idx] = H.u;
    }
}

// ---------------------------------------------------------------------------
// Kernel 1: qkv = x16 @ Wq16^T. 128x128 tile, BK=64 (6 K-steps), dbuf
// global_load_lds staging (pre-swizzled src, chunk^=row&7), vmcnt(8).
// grid (64, 9), block 256. LDS 64KB.
// ---------------------------------------------------------------------------
__global__ __launch_bounds__(256) void qkv_gemm(
    const f16* __restrict__ x16, const f16* __restrict__ w16,
    f16* __restrict__ q_, f16* __restrict__ k_, f16* __restrict__ vt_) {
    __shared__ f16 sA[2][8192], sB[2][8192];   // [128 rows][64 f16]
    const int tid = threadIdx.x;
    const int w = tid >> 6, lane = tid & 63;
    const int g = lane >> 4, q = lane & 15;
    const int m0 = blockIdx.x * 128, j0 = blockIdx.y * 128;
    const int wm = (w >> 1) * 64, wn = (w & 1) * 64;
    const bool isV = (j0 >= 768);

    const char* gA = (const char*)x16 + (size_t)m0 * 768;
    const char* gB = (const char*)w16 + (size_t)j0 * 768;
    // wave w stages rows [32w,32w+32) of A and B: 4+4 GLOAD16 per K-step.
    auto STAGE = [&](int buf, int ks) {
#pragma unroll
        for (int i = 0; i < 4; ++i) {
            const int r0 = 32 * w + i * 8;
            const int row = r0 + (lane >> 3);
            const int chs = ((lane & 7) ^ (row & 7)) << 4;
            GLOAD16(gA + (size_t)row * 768 + ks * 128 + chs, &sA[buf][r0 * 64]);
            GLOAD16(gB + (size_t)row * 768 + ks * 128 + chs, &sB[buf][r0 * 64]);
        }
    };

    f32x4 acc[4][4];
#pragma unroll
    for (int i = 0; i < 4; ++i)
#pragma unroll
        for (int j = 0; j < 4; ++j) acc[i][j] = (f32x4){0.f, 0.f, 0.f, 0.f};

    asm volatile("" ::: "memory");
    STAGE(0, 0);
    int cur = 0;
    for (int ks = 0; ks < 6; ++ks) {
        __builtin_amdgcn_s_barrier();            // prev readers of buf^1 done
        if (ks < 5) {
            STAGE(cur ^ 1, ks + 1);
            asm volatile("s_waitcnt vmcnt(8)" ::: "memory");   // tile ks landed
        } else {
            asm volatile("s_waitcnt vmcnt(0)" ::: "memory");
        }
        __builtin_amdgcn_s_barrier();

        half8 am[4][2], bn[4][2];
#pragma unroll
        for (int mi = 0; mi < 4; ++mi) {
            const int row = wm + 16 * mi + q;
#pragma unroll
            for (int k2 = 0; k2 < 2; ++k2) {
                const int ch = ((k2 * 4 + g) ^ (row & 7)) * 8;
                am[mi][k2] = *(const half8*)&sA[cur][row * 64 + ch];
            }
        }
#pragma unroll
        for (int nj = 0; nj < 4; ++nj) {
            const int row = wn + 16 * nj + q;
#pragma unroll
            for (int k2 = 0; k2 < 2; ++k2) {
                const int ch = ((k2 * 4 + g) ^ (row & 7)) * 8;
                bn[nj][k2] = *(const half8*)&sB[cur][row * 64 + ch];
            }
        }
        __builtin_amdgcn_s_setprio(1);
        if (!isV) {
#pragma unroll
            for (int mi = 0; mi < 4; ++mi)
#pragma unroll
                for (int nj = 0; nj < 4; ++nj)
#pragma unroll
                    for (int k2 = 0; k2 < 2; ++k2)
                        acc[mi][nj] = MFMA16(bn[nj][k2], am[mi][k2], acc[mi][nj]);
        } else {
#pragma unroll
            for (int mi = 0; mi < 4; ++mi)
#pragma unroll
                for (int nj = 0; nj < 4; ++nj)
#pragma unroll
                    for (int k2 = 0; k2 < 2; ++k2)
                        acc[mi][nj] = MFMA16(am[mi][k2], bn[nj][k2], acc[mi][nj]);
        }
        __builtin_amdgcn_s_setprio(0);
        cur ^= 1;
    }

    if (!isV) {
        const int t = j0 / 384;
        const float sc = (t == 0) ? 0.125f : 1.0f;
        f16* dst = (t == 0) ? q_ : k_;
#pragma unroll
        for (int nj = 0; nj < 4; ++nj) {
            const int jb = j0 + wn + 16 * nj + 4 * g;
            const int h = (jb - t * 384) >> 6, d0 = jb & 63;
#pragma unroll
            for (int mi = 0; mi < 4; ++mi) {
                const int mg = m0 + wm + 16 * mi + q;
                const int b = mg >> 10, n = mg & 1023;
                const size_t base = (size_t)(b * 6 + h) * 65536 + (size_t)n * 64 + d0;
                union { f16 x[4]; uint2 u; } H;
#pragma unroll
                for (int r = 0; r < 4; ++r) H.x[r] = (f16)(acc[mi][nj][r] * sc);
                *(uint2*)&dst[base] = H.u;
            }
        }
    } else {
#pragma unroll
        for (int nj = 0; nj < 4; ++nj) {
            const int jc = j0 + wn + 16 * nj + q;
            const int h = (jc - 768) >> 6, d = jc & 63;
#pragma unroll
            for (int mi = 0; mi < 4; ++mi) {
                const int mg = m0 + wm + 16 * mi + 4 * g;
                const int b = mg >> 10, n = mg & 1023;
                const size_t bh = (size_t)(b * 6 + h);
                union { f16 x[4]; uint2 u; } HV;
#pragma unroll
                for (int r = 0; r < 4; ++r) HV.x[r] = (f16)acc[mi][nj][r];
                *(uint2*)&vt_[bh * 65536 + (size_t)d * 1024 + n] = HV.u;
            }
        }
    }
}

// ---------------------------------------------------------------------------
// Kernel 2: fused relu-attention, single-f16, 8 waves (QBLK=128), KVBLK=64,
// dbuf 32KB LDS, vmcnt(2), setprio (unchanged from R11).
// grid 384 1D: bh = id%48 (XCD-local), qtile = id/48.
// ---------------------------------------------------------------------------
__global__ __launch_bounds__(512) void attn_mfma(
    const f16* __restrict__ q_, const f16* __restrict__ k_,
    const f16* __restrict__ vt_, const float* __restrict__ alpha,
    f16* __restrict__ ao_) {
    __shared__ f16 sK[2][4096], sV[2][4096];
    const int tid = threadIdx.x;
    const int w = tid >> 6, lane = tid & 63;
    const int g = lane >> 4, q = lane & 15;
    const int bh = blockIdx.x % 48, h = bh % 6;
    const int n0 = (blockIdx.x / 48) * 128;

    const size_t kbb = (size_t)bh * 131072;
    const int rl8 = lane >> 3, cl8 = lane & 7;

    auto STAGE = [&](int buf, int kt) {
        const size_t kb = kbb + (size_t)kt * 8192;
        const size_t vb = kbb + (size_t)kt * 128;
        const int rloc = 8 * w + rl8;
        const int chs = (cl8 ^ (rloc & 7)) << 4;
        const int ldso = 8 * w * 64;
        GLOAD16((const char*)k_ + kb + (size_t)rloc * 128 + chs, &sK[buf][ldso]);
        GLOAD16((const char*)vt_ + vb + (size_t)rloc * 2048 + chs, &sV[buf][ldso]);
    };

    const size_t qbase = (size_t)bh * 65536 + (size_t)(n0 + 16 * w + q) * 64;
    half8 Qh[2];
    Qh[0] = *(const half8*)&q_[qbase + g * 8];
    Qh[1] = *(const half8*)&q_[qbase + 32 + g * 8];
    const float al = alpha[h];
    const float cg = (1.0f - al) * (1.0f / 1024.0f);
    const bool useLin = (cg != 0.0f);

    f32x4 accP[4], accS[4];
#pragma unroll
    for (int i = 0; i < 4; ++i) {
        accP[i] = (f32x4){0.f, 0.f, 0.f, 0.f};
        accS[i] = (f32x4){0.f, 0.f, 0.f, 0.f};
    }
    float rs = 0.f;

    asm volatile("" ::: "memory");
    STAGE(0, 0);
    int cur = 0;
    for (int kt = 0; kt < 16; ++kt) {
        __builtin_amdgcn_s_barrier();
        if (kt < 15) {
            STAGE(cur ^ 1, kt + 1);
            asm volatile("s_waitcnt vmcnt(2)" ::: "memory");
        } else {
            asm volatile("s_waitcnt vmcnt(0)" ::: "memory");
        }
        __builtin_amdgcn_s_barrier();

        f32x4 sv[4];
        __builtin_amdgcn_s_setprio(1);
#pragma unroll
        for (int s = 0; s < 4; ++s) {
            f32x4 sa = (f32x4){0.f, 0.f, 0.f, 0.f};
            const int row = 16 * s + q;
#pragma unroll
            for (int k2 = 0; k2 < 2; ++k2) {
                const int ch = ((k2 * 4 + g) ^ (row & 7)) * 8;
                half8 kf = *(const half8*)&sK[cur][row * 64 + ch];
                sa = MFMA16(kf, Qh[k2], sa);
            }
            sv[s] = sa;
        }
        __builtin_amdgcn_s_setprio(0);

        uint32_t pk[4][2];
#pragma unroll
        for (int s = 0; s < 4; ++s) {
            float p0 = fmaxf(sv[s][0], 0.f), p1 = fmaxf(sv[s][1], 0.f);
            float p2 = fmaxf(sv[s][2], 0.f), p3 = fmaxf(sv[s][3], 0.f);
            rs += (p0 + p1) + (p2 + p3);
            pk[s][0] = packh((f16)p0, (f16)p1);
            pk[s][1] = packh((f16)p2, (f16)p3);
        }

#pragma unroll
        for (int t2 = 0; t2 < 2; ++t2) {
            union { uint32_t u[4]; half8 v; } fh;
#pragma unroll
            for (int r = 0; r < 4; ++r) {
                const int srcl = ((2 * g + (r >> 1)) & 3) * 16 + q;
                uint32_t a0 = __shfl(pk[2 * t2][r & 1], srcl, 64);
                uint32_t b0 = __shfl(pk[2 * t2 + 1][r & 1], srcl, 64);
                fh.u[r] = (g < 2) ? a0 : b0;
            }
            __builtin_amdgcn_s_setprio(1);
#pragma unroll
            for (int ds = 0; ds < 4; ++ds) {
                const int row = 16 * ds + q;
                const int ch = ((t2 * 4 + g) ^ (row & 7)) * 8;
                half8 vf = *(const half8*)&sV[cur][row * 64 + ch];
                accP[ds] = MFMA16(vf, fh.v, accP[ds]);
            }
            __builtin_amdgcn_s_setprio(0);
        }

        if (useLin) {
            uint32_t sk[4][2];
#pragma unroll
            for (int s = 0; s < 4; ++s) {
                sk[s][0] = packh((f16)sv[s][0], (f16)sv[s][1]);
                sk[s][1] = packh((f16)sv[s][2], (f16)sv[s][3]);
            }
#pragma unroll
            for (int t2 = 0; t2 < 2; ++t2) {
                union { uint32_t u[4]; half8 v; } fh;
#pragma unroll
                for (int r = 0; r < 4; ++r) {
                    const int srcl = ((2 * g + (r >> 1)) & 3) * 16 + q;
                    uint32_t a0 = __shfl(sk[2 * t2][r & 1], srcl, 64);
                    uint32_t b0 = __shfl(sk[2 * t2 + 1][r & 1], srcl, 64);
                    fh.u[r] = (g < 2) ? a0 : b0;
                }
#pragma unroll
                for (int ds = 0; ds < 4; ++ds) {
                    const int row = 16 * ds + q;
                    const int ch = ((t2 * 4 + g) ^ (row & 7)) * 8;
                    half8 vf = *(const half8*)&sV[cur][row * 64 + ch];
                    accS[ds] = MFMA16(vf, fh.v, accS[ds]);
                }
            }
        }
        cur ^= 1;
    }

    rs += __shfl_xor(rs, 16, 64);
    rs += __shfl_xor(rs, 32, 64);
    const float inv = al / (rs + 1e-5f);

    const int b = bh / 6;
    const size_t arow = (size_t)(b * 1024 + n0 + 16 * w + q) * 384 + h * 64;
#pragma unroll
    for (int ds = 0; ds < 4; ++ds) {
        const int d0 = 16 * ds + 4 * g;
        union { f16 x[4]; uint2 u; } H;
#pragma unroll
        for (int r = 0; r < 4; ++r)
            H.x[r] = (f16)(accP[ds][r] * inv + cg * accS[ds][r]);
        *(uint2*)&ao_[arow + d0] = H.u;
    }
}

// ---------------------------------------------------------------------------
// Kernel 3: out = ao @ Wp16^T + bias. 64x128 tile, BK=64 (6 K-steps), dbuf
// staging, vmcnt(6). grid (128, 3), block 256. LDS 48KB.
// Wave w stages A rows [16w,16w+16) (2 GLOADs) + B rows [32w,32w+32) (4).
// ---------------------------------------------------------------------------
__global__ __launch_bounds__(256) void proj_gemm(
    const f16* __restrict__ a_, const f16* __restrict__ wp16,
    const float* __restrict__ bias, float* __restrict__ out) {
    __shared__ f16 sA[2][4096], sB[2][8192];   // [rows][64 f16]
    const int tid = threadIdx.x;
    const int w = tid >> 6, lane = tid & 63;
    const int g = lane >> 4, q = lane & 15;
    const int m0 = blockIdx.x * 64, j0 = blockIdx.y * 128;
    const int wm = (w >> 1) * 32, wn = (w & 1) * 64;

    const char* gA = (const char*)a_ + (size_t)m0 * 768;
    const char* gB = (const char*)wp16 + (size_t)j0 * 768;
    auto STAGE = [&](int buf, int ks) {
#pragma unroll
        for (int i = 0; i < 2; ++i) {
            const int r0 = 16 * w + i * 8;
            const int row = r0 + (lane >> 3);
            const int chs = ((lane & 7) ^ (row & 7)) << 4;
            GLOAD16(gA + (size_t)row * 768 + ks * 128 + chs, &sA[buf][r0 * 64]);
        }
#pragma unroll
        for (int i = 0; i < 4; ++i) {
            const int r0 = 32 * w + i * 8;
            const int row = r0 + (lane >> 3);
            const int chs = ((lane & 7) ^ (row & 7)) << 4;
            GLOAD16(gB + (size_t)row * 768 + ks * 128 + chs, &sB[buf][r0 * 64]);
        }
    };

    f32x4 acc[2][4];
#pragma unroll
    for (int i = 0; i < 2; ++i)
#pragma unroll
        for (int j = 0; j < 4; ++j) acc[i][j] = (f32x4){0.f, 0.f, 0.f, 0.f};

    asm volatile("" ::: "memory");
    STAGE(0, 0);
    int cur = 0;
    for (int ks = 0; ks < 6; ++ks) {
        __builtin_amdgcn_s_barrier();
        if (ks < 5) {
            STAGE(cur ^ 1, ks + 1);
            asm volatile("s_waitcnt vmcnt(6)" ::: "memory");
        } else {
            asm volatile("s_waitcnt vmcnt(0)" ::: "memory");
        }
        __builtin_amdgcn_s_barrier();

        half8 am[2][2], bn[4][2];
#pragma unroll
        for (int mi = 0; mi < 2; ++mi) {
            const int row = wm + 16 * mi + q;
#pragma unroll
            for (int k2 = 0; k2 < 2; ++k2) {
                const int ch = ((k2 * 4 + g) ^ (row & 7)) * 8;
                am[mi][k2] = *(const half8*)&sA[cur][row * 64 + ch];
            }
        }
#pragma unroll
        for (int nj = 0; nj < 4; ++nj) {
            const int row = wn + 16 * nj + q;
#pragma unroll
            for (int k2 = 0; k2 < 2; ++k2) {
                const int ch = ((k2 * 4 + g) ^ (row & 7)) * 8;
                bn[nj][k2] = *(const half8*)&sB[cur][row * 64 + ch];
            }
        }
        __builtin_amdgcn_s_setprio(1);
#pragma unroll
        for (int mi = 0; mi < 2; ++mi)
#pragma unroll
            for (int nj = 0; nj < 4; ++nj)
#pragma unroll
                for (int k2 = 0; k2 < 2; ++k2)
                    acc[mi][nj] = MFMA16(bn[nj][k2], am[mi][k2], acc[mi][nj]);
        __builtin_amdgcn_s_setprio(0);
        cur ^= 1;
    }

#pragma unroll
    for (int nj = 0; nj < 4; ++nj) {
        const int jb = j0 + wn + 16 * nj + 4 * g;
        const float4 bb = *(const float4*)&bias[jb];
#pragma unroll
        for (int mi = 0; mi < 2; ++mi) {
            const int m = m0 + wm + 16 * mi + q;
            float4 o;
            o.x = acc[mi][nj][0] + bb.x;
            o.y = acc[mi][nj][1] + bb.y;
            o.z = acc[mi][nj][2] + bb.z;
            o.w = acc[mi][nj][3] + bb.w;
            *(float4*)&out[(size_t)m * 384 + jb] = o;
        }
    }
}

// ---------------------------------------------------------------------------
extern "C" void kernel_launch(void* const* d_in, const int* in_sizes, int n_in,
                              void* d_out, int out_size, void* d_ws, size_t ws_size,
                              hipStream_t stream) {
    const float* x     = (const float*)d_in[0];
    const float* Wqkv  = (const float*)d_in[1];
    const float* Wproj = (const float*)d_in[2];
    const float* bproj = (const float*)d_in[3];
    const float* alpha = (const float*)d_in[4];
    float* out = (float*)d_out;

    f16* ws = (f16*)d_ws;
    const size_t XE = 8192 * 384;
    const size_t WQ = 1152 * 384;
    const size_t WP = 384 * 384;
    const size_t QE = 48 * 1024 * 64;

    f16* x16  = ws;            f16* wq16 = x16 + XE;
    f16* wp16 = wq16 + WQ;
    f16* qv   = wp16 + WP;     f16* kv   = qv + QE;
    f16* vt   = kv + QE;       f16* ao   = vt + QE;

    convert_all<<<1024, 256, 0, stream>>>(x, Wqkv, Wproj, x16, wq16, wp16);
    qkv_gemm<<<dim3(64, 9), 256, 0, stream>>>(x16, wq16, qv, kv, vt);
    attn_mfma<<<384, 512, 0, stream>>>(qv, kv, vt, alpha, ao);
    proj_gemm<<<dim3(128, 3), 256, 0, stream>>>(ao, wp16, bproj, out);
}